// Round 11
// baseline (202.443 us; speedup 1.0000x reference)
//
#include <hip/hip_runtime.h>

constexpr int N_NODES = 50000;
constexpr int N_REL   = 4;
constexpr int EMBD    = 128;
constexpr int N_HEAD  = 4;
constexpr int HS      = 32;
constexpr int N_EDGE  = 400000;
constexpr int N_ROWS  = N_REL * N_NODES;        // 200000 segment rows

typedef __attribute__((ext_vector_type(8))) short bf16x8;
typedef __attribute__((ext_vector_type(4))) float f32x4;
typedef unsigned short ushort_t;
typedef unsigned int   uint_t;

__device__ __forceinline__ float b2f(ushort_t u) {
    return __uint_as_float(((unsigned int)u) << 16);
}
__device__ __forceinline__ ushort_t f2b(float f) {
    unsigned int u = __float_as_uint(f);
    u += 0x7FFF + ((u >> 16) & 1);   // round-to-nearest-even
    return (ushort_t)(u >> 16);
}
__device__ __forceinline__ float lo_bf(uint_t u) {   // bf16 pair: low elem
    return __uint_as_float(u << 16);
}
__device__ __forceinline__ float hi_bf(uint_t u) {   // bf16 pair: high elem
    return __uint_as_float(u & 0xFFFF0000u);
}

// ---------------------------------------------------------------------------
// prep: Wb = bf16({tokeys,toqueries,tovals}), Ub = bf16(unify), HIST = 0.
// ---------------------------------------------------------------------------
__global__ __launch_bounds__(256) void prep_kernel(
    const float* __restrict__ tk, const float* __restrict__ tq,
    const float* __restrict__ tv, const float* __restrict__ un,
    ushort_t* __restrict__ Wb, ushort_t* __restrict__ Ub, int* __restrict__ HIST)
{
    int idx = blockIdx.x * 256 + threadIdx.x;      // grid covers 200192
    if (idx < 49152) {
        int m = idx >> 14, i2 = idx & 16383;
        const float* src = (m == 0) ? tk : (m == 1) ? tq : tv;
        Wb[idx] = f2b(src[i2]);
    }
    if (idx < 65536) Ub[idx] = f2b(un[idx]);
    if (idx < N_ROWS) HIST[idx] = 0;
}

// ---------------------------------------------------------------------------
// MFMA projection: K/Q/V for all 4 relations in ONE pass over x. KNOWN GOOD (r8-10).
// ---------------------------------------------------------------------------
__global__ __launch_bounds__(512) void proj_mfma(
    const float* __restrict__ x, const ushort_t* __restrict__ Wb,
    ushort_t* __restrict__ K, ushort_t* __restrict__ Q, ushort_t* __restrict__ V)
{
    __shared__ ushort_t xs[128 * 136];   // [node][k] bf16, stride 272B

    const int t    = threadIdx.x;        // 0..511
    const int lane = t & 63;
    const int w    = t >> 6;             // wave 0..7
    const int n0   = blockIdx.x * 128;

    {   // stage x (fp32 global) -> bf16 LDS
        const float4* x4 = (const float4*)(x + (size_t)n0 * 128);
        for (int idx = t; idx < 128 * 32; idx += 512) {
            int nn = idx >> 5, c4 = idx & 31;
            float4 v = make_float4(0.f, 0.f, 0.f, 0.f);
            if (n0 + nn < N_NODES) v = x4[idx];
            ushort4 b = make_ushort4(f2b(v.x), f2b(v.y), f2b(v.z), f2b(v.w));
            *(ushort4*)&xs[nn * 136 + c4 * 4] = b;
        }
    }
    __syncthreads();

    const int row  = lane & 15;     // A node-row / B col / D col
    const int kg   = lane >> 4;     // k-group (8 elems each)
    const int rgrp = lane >> 4;     // D row-group

    #pragma unroll
    for (int m = 0; m < 3; m++) {
        ushort_t* P = (m == 0) ? K : (m == 1) ? Q : V;
        #pragma unroll 1
        for (int r = 0; r < N_REL; r++) {
            f32x4 acc[8];
            #pragma unroll
            for (int f = 0; f < 8; f++) {
                const int h = f >> 1;
                bf16x8 a = *(const bf16x8*)&xs[(w * 16 + row) * 136 + h * 32 + kg * 8];
                const ushort_t* bp = Wb + ((((m * 4 + r) * 4 + h) * 32 + (f & 1) * 16 + row) * 32) + kg * 8;
                bf16x8 b = *(const bf16x8*)bp;
                acc[f] = __builtin_amdgcn_mfma_f32_16x16x32_bf16(
                             a, b, (f32x4){0.f, 0.f, 0.f, 0.f}, 0, 0, 0);
            }
            #pragma unroll
            for (int f = 0; f < 8; f++) {
                #pragma unroll
                for (int reg = 0; reg < 4; reg++) {
                    int n = n0 + w * 16 + rgrp * 4 + reg;
                    if (n < N_NODES)
                        P[((size_t)r * N_NODES + n) * 128 + f * 16 + row] = f2b(acc[f][reg]);
                }
            }
        }
    }
}

// ---------------------------------------------------------------------------
// CSR build: histogram -> 3-phase deterministic scan -> scatter. KNOWN GOOD.
// ---------------------------------------------------------------------------
__global__ __launch_bounds__(256) void hist_kernel(
    const int* __restrict__ esub, const int* __restrict__ epred, int* __restrict__ HIST)
{
    int e = blockIdx.x * 256 + threadIdx.x;
    if (e < N_EDGE) atomicAdd(&HIST[epred[e] * N_NODES + esub[e]], 1);
}

__global__ __launch_bounds__(256) void scan_p1(      // per-block totals
    const int* __restrict__ HIST, int* __restrict__ SUMS)
{
    int b = blockIdx.x, t = threadIdx.x;
    int base = b * 1024 + t * 4;
    int s = 0;
    #pragma unroll
    for (int k = 0; k < 4; k++) if (base + k < N_ROWS) s += HIST[base + k];
    __shared__ int red[256];
    red[t] = s; __syncthreads();
    for (int st = 128; st > 0; st >>= 1) {
        if (t < st) red[t] += red[t + st];
        __syncthreads();
    }
    if (t == 0) SUMS[b] = red[0];
}

__global__ __launch_bounds__(256) void scan_p2(      // scan the 196 totals
    const int* __restrict__ SUMS, int* __restrict__ SOFF, int* __restrict__ OFFS)
{
    int t = threadIdx.x;
    __shared__ int sh[256];
    int o = (t < 196) ? SUMS[t] : 0;
    sh[t] = o; __syncthreads();
    for (int st = 1; st < 256; st <<= 1) {
        int v = (t >= st) ? sh[t - st] : 0;
        __syncthreads();
        sh[t] += v;
        __syncthreads();
    }
    if (t < 196) SOFF[t] = sh[t] - o;                // exclusive
    if (t == 0)  OFFS[N_ROWS] = sh[255];             // total == N_EDGE
}

__global__ __launch_bounds__(256) void scan_p3(      // full exclusive scan (+CURSOR)
    const int* __restrict__ HIST, const int* __restrict__ SOFF,
    int* __restrict__ OFFS, int* __restrict__ CURSOR)
{
    int b = blockIdx.x, t = threadIdx.x;
    int base = b * 1024 + t * 4;
    int v[4], tot = 0;
    #pragma unroll
    for (int k = 0; k < 4; k++) {
        v[k] = (base + k < N_ROWS) ? HIST[base + k] : 0;
        tot += v[k];
    }
    __shared__ int sh[256];
    sh[t] = tot; __syncthreads();
    for (int st = 1; st < 256; st <<= 1) {
        int q = (t >= st) ? sh[t - st] : 0;
        __syncthreads();
        sh[t] += q;
        __syncthreads();
    }
    int run = SOFF[b] + (sh[t] - tot);
    #pragma unroll
    for (int k = 0; k < 4; k++) {
        if (base + k < N_ROWS) { OFFS[base + k] = run; CURSOR[base + k] = run; run += v[k]; }
    }
}

__global__ __launch_bounds__(256) void scatter_kernel(
    const int* __restrict__ esub, const int* __restrict__ epred, const int* __restrict__ eobj,
    int* __restrict__ CURSOR, int* __restrict__ OBJS)
{
    int e = blockIdx.x * 256 + threadIdx.x;
    if (e < N_EDGE) {
        int row = epred[e] * N_NODES + esub[e];
        int pos = atomicAdd(&CURSOR[row], 1);
        OBJS[pos] = eobj[e];                       // store obj, not edge id
    }
}

// ---------------------------------------------------------------------------
// FUSED dot+softmax+aggregate, TWO rows per wave (adjacent rows 2b, 2b+1 —
// their OFFS ranges share a boundary: 3 scalar loads). Two independent gather
// chains in flight per wave (latency-bound fix: avg degree 2 gives no
// in-row pipelining).
// Adjacent-pair lane map: lane l owns j=2l,2l+1 (head g=l>>4 — butterfly
// stays 4 rounds over 16 lanes). All Q/V/K/AGG accesses are ONE uint per
// lane at base64+lane: a single coalesced 256B transaction per row access.
// ---------------------------------------------------------------------------
__global__ __launch_bounds__(256) void agg_fused(
    const int* __restrict__ OFFS, const int* __restrict__ OBJS,
    const uint_t* __restrict__ K64, const uint_t* __restrict__ Q64,
    const uint_t* __restrict__ V64, uint_t* __restrict__ AGG64)
{
    const int t    = threadIdx.x;
    const int lane = t & 63;
    const int rowA = (blockIdx.x * 4 + (t >> 6)) * 2;   // grid 25000: covers 200000 rows
    const int rowB = rowA + 1;

    const int begA = OFFS[rowA];
    const int endA = OFFS[rowA + 1];          // == begB
    const int endB = OFFS[rowA + 2];

    const bool hasA = begA < endA;
    const bool hasB = endA < endB;

    const unsigned rA64 = (unsigned)rowA * 64u;
    const unsigned rB64 = rA64 + 64u;

    float kAlo = 0.f, kAhi = 0.f, kBlo = 0.f, kBhi = 0.f;
    if (hasA) { uint_t ku = K64[rA64 + lane]; kAlo = lo_bf(ku); kAhi = hi_bf(ku); }
    if (hasB) { uint_t ku = K64[rB64 + lane]; kBlo = lo_bf(ku); kBhi = hi_bf(ku); }

    // gather bases (uint units): (pred*N + obj)*64
    const unsigned nbA = (unsigned)(rowA / N_NODES) * (unsigned)N_NODES * 64u;
    const unsigned nbB = (unsigned)(rowB / N_NODES) * (unsigned)N_NODES * 64u;

    float accAlo = 0.f, accAhi = 0.f, segA = 0.f;
    float accBlo = 0.f, accBhi = 0.f, segB = 0.f;

    int iA = begA, iB = endA;
    while (iA < endA || iB < endB) {          // wave-uniform condition
        const bool dA = iA < endA, dB = iB < endB;
        uint_t qAu = 0, vAu = 0, qBu = 0, vBu = 0;
        if (dA) {
            unsigned off = nbA + (unsigned)OBJS[iA] * 64u;
            qAu = Q64[off + lane]; vAu = V64[off + lane];
        }
        if (dB) {
            unsigned off = nbB + (unsigned)OBJS[iB] * 64u;
            qBu = Q64[off + lane]; vBu = V64[off + lane];
        }
        float pA = kAlo * lo_bf(qAu) + kAhi * hi_bf(qAu);
        float pB = kBlo * lo_bf(qBu) + kBhi * hi_bf(qBu);
        #pragma unroll
        for (int m = 1; m < 16; m <<= 1) {    // 16-lane (one head) butterfly
            pA += __shfl_xor(pA, m, 64);
            pB += __shfl_xor(pB, m, 64);
        }
        if (dA) {
            float ex = __expf(pA);
            accAlo += ex * lo_bf(vAu); accAhi += ex * hi_bf(vAu); segA += ex;
            iA++;
        }
        if (dB) {
            float ex = __expf(pB);
            accBlo += ex * lo_bf(vBu); accBhi += ex * hi_bf(vBu); segB += ex;
            iB++;
        }
    }

    uint_t outA = 0u, outB = 0u;
    if (hasA) {
        float inv = 1.0f / segA;
        outA = (uint_t)f2b(accAlo * inv) | ((uint_t)f2b(accAhi * inv) << 16);
    }
    if (hasB) {
        float inv = 1.0f / segB;
        outB = (uint_t)f2b(accBlo * inv) | ((uint_t)f2b(accBhi * inv) << 16);
    }
    AGG64[rA64 + lane] = outA;
    AGG64[rB64 + lane] = outB;
}

// ---------------------------------------------------------------------------
// out[n][i] = relu( sum_r sum_j U[r][i][j] * AGGnorm[r][n][j] )  — bf16 MFMA,
// fp32 accum. KNOWN GOOD (rounds 5-10).
// ---------------------------------------------------------------------------
__global__ __launch_bounds__(256) void unify_mfma(
    const ushort_t* __restrict__ AGG,
    const ushort_t* __restrict__ Ub, float* __restrict__ out)
{
    __shared__ ushort_t As[64 * 136];    // A tile: [node][k] bf16
    __shared__ ushort_t Bs[128 * 136];   // B tile: [i][k] bf16

    const int t    = threadIdx.x;
    const int lane = t & 63;
    const int w    = t >> 6;
    const int n0   = blockIdx.x * 64;

    f32x4 acc[8];
    #pragma unroll
    for (int f = 0; f < 8; f++) acc[f] = (f32x4){0.f, 0.f, 0.f, 0.f};

    for (int r = 0; r < N_REL; r++) {
        __syncthreads();

        {   // stage A: AGG[r][n0..n0+63][0..127] plain bf16 copy (16B chunks)
            const uint4* a4 = (const uint4*)(AGG + ((size_t)r * N_NODES + n0) * 128);
            for (int idx = t; idx < 64 * 16; idx += 256) {
                int nn = idx >> 4, c = idx & 15;
                uint4 v = make_uint4(0, 0, 0, 0);
                if (n0 + nn < N_NODES) v = a4[idx];
                *(uint4*)&As[nn * 136 + c * 8] = v;
            }
        }
        {   // stage B: Ub[r] straight copy (L2-hot)
            const uint4* u4 = (const uint4*)(Ub + (size_t)r * 128 * 128);
            for (int idx = t; idx < 128 * 16; idx += 256) {
                int i = idx >> 4, c = idx & 15;
                *(uint4*)&Bs[i * 136 + c * 8] = u4[idx];
            }
        }
        __syncthreads();

        const int row = lane & 15;     // A row / B col
        const int kg  = lane >> 4;     // k-group
        #pragma unroll
        for (int ks = 0; ks < 4; ks++) {
            const int kofs = ks * 32 + kg * 8;
            bf16x8 a = *(const bf16x8*)&As[(w * 16 + row) * 136 + kofs];
            #pragma unroll
            for (int f = 0; f < 8; f++) {
                bf16x8 b = *(const bf16x8*)&Bs[(f * 16 + row) * 136 + kofs];
                acc[f] = __builtin_amdgcn_mfma_f32_16x16x32_bf16(a, b, acc[f], 0, 0, 0);
            }
        }
    }

    const int col  = lane & 15;
    const int rgrp = lane >> 4;
    #pragma unroll
    for (int f = 0; f < 8; f++) {
        #pragma unroll
        for (int reg = 0; reg < 4; reg++) {
            int n = n0 + w * 16 + rgrp * 4 + reg;
            if (n < N_NODES)
                out[(size_t)n * 128 + f * 16 + col] = fmaxf(acc[f][reg], 0.f);
        }
    }
}

extern "C" void kernel_launch(void* const* d_in, const int* in_sizes, int n_in,
                              void* d_out, int out_size, void* d_ws, size_t ws_size,
                              hipStream_t stream)
{
    const float* x  = (const float*)d_in[0];
    const float* tk = (const float*)d_in[1];
    const float* tq = (const float*)d_in[2];
    const float* tv = (const float*)d_in[3];
    const float* un = (const float*)d_in[4];
    const int* esub  = (const int*)d_in[5];
    const int* epred = (const int*)d_in[6];
    const int* eobj  = (const int*)d_in[7];
    float* out = (float*)d_out;

    // Workspace layout (bytes), identical offsets to rounds 9-10 (proven):
    //   BK:   [R][N][128] bf16 (K)                       @ 0            (51,200,000)
    //   BQ:   [R][N][128] bf16 (Q)                       @ 51,200,000   (51,200,000)
    //   BV:   [R][N][128] bf16 (V)                       @ 102,400,000  (51,200,000)
    //   (unused)                                         @ 153,600,000  ( 6,400,000)
    //   HIST/CURSOR: [200000] int                        @ 160,000,000  (   800,000)
    //   SUMS: [196] int (pad 4096)                       @ 160,800,000  (     4,096)
    //   SOFF: [196] int (pad 4096)                       @ 160,804,096  (     4,096)
    //   OFFS: [200001] int                               @ 160,808,192  (   800,004 pad->807,808)
    //   OBJS: [400000] int                               @ 161,616,000  ( 1,600,000)
    //   Ub:   [R][128][128] bf16                         @ 163,216,000  (   131,072)
    //   Wb:   [3][R][H][32][32] bf16                     @ 163,347,072  (    98,304)
    //   AGG:  [R*N][128] bf16                            @ 165,000,000  (51,200,000)
    char* ws = (char*)d_ws;
    ushort_t* BK  = (ushort_t*)(ws);
    ushort_t* BQ  = (ushort_t*)(ws + 51200000);
    ushort_t* BV  = (ushort_t*)(ws + 102400000);
    int*      HIST= (int*)     (ws + 160000000);   // doubles as CURSOR
    int*      SUMS= (int*)     (ws + 160800000);
    int*      SOFF= (int*)     (ws + 160804096);
    int*      OFFS= (int*)     (ws + 160808192);
    int*      OBJS= (int*)     (ws + 161616000);
    ushort_t* Ub  = (ushort_t*)(ws + 163216000);
    ushort_t* Wb  = (ushort_t*)(ws + 163347072);
    ushort_t* AGG = (ushort_t*)(ws + 165000000);

    // prep: casts + HIST zero (1 launch)
    prep_kernel<<<(N_ROWS + 255) / 256, 256, 0, stream>>>(tk, tq, tv, un, Wb, Ub, HIST);

    // CSR build
    hist_kernel<<<(N_EDGE + 255) / 256, 256, 0, stream>>>(esub, epred, HIST);
    scan_p1<<<196, 256, 0, stream>>>(HIST, SUMS);
    scan_p2<<<1, 256, 0, stream>>>(SUMS, SOFF, OFFS);
    scan_p3<<<196, 256, 0, stream>>>(HIST, SOFF, OFFS, HIST);  // OFFS + CURSOR (reuses HIST)
    scatter_kernel<<<(N_EDGE + 255) / 256, 256, 0, stream>>>(esub, epred, eobj, HIST, OBJS);

    // K/Q/V for all relations in one MFMA pass
    proj_mfma<<<(N_NODES + 127) / 128, 512, 0, stream>>>(x, Wb, BK, BQ, BV);

    // fused dot + softmax + aggregate (2 rows per wave, uint-packed accesses)
    agg_fused<<<N_ROWS / 8, 256, 0, stream>>>(OFFS, OBJS,
                                              (const uint_t*)BK, (const uint_t*)BQ,
                                              (const uint_t*)BV, (uint_t*)AGG);

    unify_mfma<<<(N_NODES + 63) / 64, 256, 0, stream>>>(AGG, Ub, out);
}

// Round 12
// 178.337 us; speedup vs baseline: 1.1352x; 1.1352x over previous
//
#include <hip/hip_runtime.h>

constexpr int N_NODES = 50000;
constexpr int N_REL   = 4;
constexpr int EMBD    = 128;
constexpr int N_HEAD  = 4;
constexpr int HS      = 32;
constexpr int N_EDGE  = 400000;
constexpr int N_ROWS  = N_REL * N_NODES;        // 200000 segment rows

typedef __attribute__((ext_vector_type(8))) short bf16x8;
typedef __attribute__((ext_vector_type(4))) float f32x4;
typedef unsigned short ushort_t;
typedef unsigned int   uint_t;

__device__ __forceinline__ ushort_t f2b(float f) {
    unsigned int u = __float_as_uint(f);
    u += 0x7FFF + ((u >> 16) & 1);   // round-to-nearest-even
    return (ushort_t)(u >> 16);
}
__device__ __forceinline__ float lo_bf(uint_t u) {   // bf16 pair: low elem
    return __uint_as_float(u << 16);
}
__device__ __forceinline__ float hi_bf(uint_t u) {   // bf16 pair: high elem
    return __uint_as_float(u & 0xFFFF0000u);
}

// ---------------------------------------------------------------------------
// prep: XB = bf16(x) (the gather target, 12.8 MB — L2/L3-resident), HIST = 0.
// ---------------------------------------------------------------------------
__global__ __launch_bounds__(256) void prep_kernel(
    const float* __restrict__ x, ushort_t* __restrict__ XB, int* __restrict__ HIST)
{
    int idx = blockIdx.x * 256 + threadIdx.x;      // grid 25000 = 6.4M threads exact
    XB[idx] = f2b(x[idx]);
    if (idx < N_ROWS) HIST[idx] = 0;
}

// ---------------------------------------------------------------------------
// Fused small matrices (each output = one 32-MAC dot, fp32 math -> bf16):
//  Ct[r][h][b][a] = sum_s tokeys[r,h,s,a] * toqueries[r,h,s,b]
//     => dot_h(sub,obj) = (Ct-proj of x_sub) . x_obj   [K^T Q bilinear form]
//  Mb[r][i][h*32+k] = sum_s unify[r,i,h*32+s] * tovals[r,h,s,k]
//     => U_r @ blockdiag(tovals_r): unify consumes x-space aggregates directly.
// ---------------------------------------------------------------------------
__global__ __launch_bounds__(256) void fuse_cm(
    const float* __restrict__ tk, const float* __restrict__ tq,
    const float* __restrict__ tv, const float* __restrict__ un,
    ushort_t* __restrict__ Ct, ushort_t* __restrict__ Mb)
{
    int idx = blockIdx.x * 256 + threadIdx.x;      // 320 blocks = 81920 exact
    if (idx < 16384) {
        int a = idx & 31, b = (idx >> 5) & 31, rh = idx >> 10;   // rh = r*4+h
        const float* tks = tk + rh * 1024;         // [s][a], 32x32
        const float* tqs = tq + rh * 1024;         // [s][b]
        float acc = 0.f;
        #pragma unroll
        for (int s = 0; s < 32; s++) acc += tks[s * 32 + a] * tqs[s * 32 + b];
        Ct[idx] = f2b(acc);                        // idx == (rh*32 + b)*32 + a
    } else {
        int j  = idx - 16384;                      // Mb flat index: [r][i][jc]
        int jc = j & 127, i = (j >> 7) & 127, r = j >> 14;
        int h = jc >> 5, k = jc & 31;
        const float* us  = un + ((size_t)(r * 128 + i)) * 128 + h * 32;  // U[r,i,h*32+s]
        const float* tvs = tv + (r * 4 + h) * 1024 + k;                  // tovals[r,h,s,k]
        float acc = 0.f;
        #pragma unroll
        for (int s = 0; s < 32; s++) acc += us[s] * tvs[s * 32];
        Mb[j] = f2b(acc);
    }
}

// ---------------------------------------------------------------------------
// MFMA projection, single output: Kt[r][n][h*32+b] = sum_a Ct[r,h,b,a]*x[n,h*32+a].
// Structure identical to the proven r8-11 proj (same fragment maps), with the
// m-loop removed and weights = Ct. A-tile staged from XB (bf16 copy).
// ---------------------------------------------------------------------------
__global__ __launch_bounds__(512) void proj_mfma(
    const ushort_t* __restrict__ XB, const ushort_t* __restrict__ Ct,
    ushort_t* __restrict__ KT)
{
    __shared__ ushort_t xs[128 * 136];   // [node][k] bf16, stride 272B

    const int t    = threadIdx.x;        // 0..511
    const int lane = t & 63;
    const int w    = t >> 6;             // wave 0..7
    const int n0   = blockIdx.x * 128;

    {   // stage XB tile (bf16, 16B chunks)
        const uint4* x4 = (const uint4*)(XB + (size_t)n0 * 128);
        for (int idx = t; idx < 128 * 16; idx += 512) {
            int nn = idx >> 4, c = idx & 15;
            uint4 v = make_uint4(0, 0, 0, 0);
            if (n0 + nn < N_NODES) v = x4[idx];
            *(uint4*)&xs[nn * 136 + c * 8] = v;
        }
    }
    __syncthreads();

    const int row  = lane & 15;     // A node-row / B col / D col
    const int kg   = lane >> 4;     // k-group (8 elems each)
    const int rgrp = lane >> 4;     // D row-group

    #pragma unroll 1
    for (int r = 0; r < N_REL; r++) {
        f32x4 acc[8];
        #pragma unroll
        for (int f = 0; f < 8; f++) {
            const int h = f >> 1;
            bf16x8 a = *(const bf16x8*)&xs[(w * 16 + row) * 136 + h * 32 + kg * 8];
            const ushort_t* bp = Ct + (((r * 4 + h) * 32 + (f & 1) * 16 + row) * 32) + kg * 8;
            bf16x8 b = *(const bf16x8*)bp;
            acc[f] = __builtin_amdgcn_mfma_f32_16x16x32_bf16(
                         a, b, (f32x4){0.f, 0.f, 0.f, 0.f}, 0, 0, 0);
        }
        #pragma unroll
        for (int f = 0; f < 8; f++) {
            #pragma unroll
            for (int reg = 0; reg < 4; reg++) {
                int n = n0 + w * 16 + rgrp * 4 + reg;
                if (n < N_NODES)
                    KT[((size_t)r * N_NODES + n) * 128 + f * 16 + row] = f2b(acc[f][reg]);
            }
        }
    }
}

// ---------------------------------------------------------------------------
// CSR build: histogram -> 3-phase deterministic scan -> scatter. KNOWN GOOD.
// ---------------------------------------------------------------------------
__global__ __launch_bounds__(256) void hist_kernel(
    const int* __restrict__ esub, const int* __restrict__ epred, int* __restrict__ HIST)
{
    int e = blockIdx.x * 256 + threadIdx.x;
    if (e < N_EDGE) atomicAdd(&HIST[epred[e] * N_NODES + esub[e]], 1);
}

__global__ __launch_bounds__(256) void scan_p1(      // per-block totals
    const int* __restrict__ HIST, int* __restrict__ SUMS)
{
    int b = blockIdx.x, t = threadIdx.x;
    int base = b * 1024 + t * 4;
    int s = 0;
    #pragma unroll
    for (int k = 0; k < 4; k++) if (base + k < N_ROWS) s += HIST[base + k];
    __shared__ int red[256];
    red[t] = s; __syncthreads();
    for (int st = 128; st > 0; st >>= 1) {
        if (t < st) red[t] += red[t + st];
        __syncthreads();
    }
    if (t == 0) SUMS[b] = red[0];
}

__global__ __launch_bounds__(256) void scan_p2(      // scan the 196 totals
    const int* __restrict__ SUMS, int* __restrict__ SOFF, int* __restrict__ OFFS)
{
    int t = threadIdx.x;
    __shared__ int sh[256];
    int o = (t < 196) ? SUMS[t] : 0;
    sh[t] = o; __syncthreads();
    for (int st = 1; st < 256; st <<= 1) {
        int v = (t >= st) ? sh[t - st] : 0;
        __syncthreads();
        sh[t] += v;
        __syncthreads();
    }
    if (t < 196) SOFF[t] = sh[t] - o;                // exclusive
    if (t == 0)  OFFS[N_ROWS] = sh[255];             // total == N_EDGE
}

__global__ __launch_bounds__(256) void scan_p3(      // full exclusive scan (+CURSOR)
    const int* __restrict__ HIST, const int* __restrict__ SOFF,
    int* __restrict__ OFFS, int* __restrict__ CURSOR)
{
    int b = blockIdx.x, t = threadIdx.x;
    int base = b * 1024 + t * 4;
    int v[4], tot = 0;
    #pragma unroll
    for (int k = 0; k < 4; k++) {
        v[k] = (base + k < N_ROWS) ? HIST[base + k] : 0;
        tot += v[k];
    }
    __shared__ int sh[256];
    sh[t] = tot; __syncthreads();
    for (int st = 1; st < 256; st <<= 1) {
        int q = (t >= st) ? sh[t - st] : 0;
        __syncthreads();
        sh[t] += q;
        __syncthreads();
    }
    int run = SOFF[b] + (sh[t] - tot);
    #pragma unroll
    for (int k = 0; k < 4; k++) {
        if (base + k < N_ROWS) { OFFS[base + k] = run; CURSOR[base + k] = run; run += v[k]; }
    }
}

__global__ __launch_bounds__(256) void scatter_kernel(
    const int* __restrict__ esub, const int* __restrict__ epred, const int* __restrict__ eobj,
    int* __restrict__ CURSOR, int* __restrict__ OBJS)
{
    int e = blockIdx.x * 256 + threadIdx.x;
    if (e < N_EDGE) {
        int row = epred[e] * N_NODES + esub[e];
        int pos = atomicAdd(&CURSOR[row], 1);
        OBJS[pos] = eobj[e];                       // store obj, not edge id
    }
}

// ---------------------------------------------------------------------------
// FUSED dot+softmax+aggregate in X-SPACE, two rows per wave (proven r11
// structure). Per edge: ONE 256B gather of x_obj from the 12.8MB XB buffer
// (L2/L3-resident) — it feeds BOTH the bilinear dot (vs row-local Kt) AND the
// aggregation. AGGX[row] = sum_e ex * x_obj / sum_e ex (per-head normalized).
// ---------------------------------------------------------------------------
__global__ __launch_bounds__(256) void agg_fused(
    const int* __restrict__ OFFS, const int* __restrict__ OBJS,
    const uint_t* __restrict__ KT64, const uint_t* __restrict__ XB64,
    uint_t* __restrict__ AGG64)
{
    const int t    = threadIdx.x;
    const int lane = t & 63;
    const int rowA = (blockIdx.x * 4 + (t >> 6)) * 2;   // grid 25000: 200000 rows
    const int begA = OFFS[rowA];
    const int endA = OFFS[rowA + 1];          // == begB
    const int endB = OFFS[rowA + 2];

    const bool hasA = begA < endA;
    const bool hasB = endA < endB;

    const unsigned rA64 = (unsigned)rowA * 64u;
    const unsigned rB64 = rA64 + 64u;

    float kAlo = 0.f, kAhi = 0.f, kBlo = 0.f, kBhi = 0.f;
    if (hasA) { uint_t ku = KT64[rA64 + lane]; kAlo = lo_bf(ku); kAhi = hi_bf(ku); }
    if (hasB) { uint_t ku = KT64[rB64 + lane]; kBlo = lo_bf(ku); kBhi = hi_bf(ku); }

    float accAlo = 0.f, accAhi = 0.f, segA = 0.f;
    float accBlo = 0.f, accBhi = 0.f, segB = 0.f;

    int iA = begA, iB = endA;
    while (iA < endA || iB < endB) {          // wave-uniform condition
        const bool dA = iA < endA, dB = iB < endB;
        uint_t xAu = 0, xBu = 0;
        if (dA) xAu = XB64[(unsigned)OBJS[iA] * 64u + lane];
        if (dB) xBu = XB64[(unsigned)OBJS[iB] * 64u + lane];
        float pA = kAlo * lo_bf(xAu) + kAhi * hi_bf(xAu);
        float pB = kBlo * lo_bf(xBu) + kBhi * hi_bf(xBu);
        #pragma unroll
        for (int m = 1; m < 16; m <<= 1) {    // 16-lane (one head) butterfly
            pA += __shfl_xor(pA, m, 64);
            pB += __shfl_xor(pB, m, 64);
        }
        if (dA) {
            float ex = __expf(pA);
            accAlo += ex * lo_bf(xAu); accAhi += ex * hi_bf(xAu); segA += ex;
            iA++;
        }
        if (dB) {
            float ex = __expf(pB);
            accBlo += ex * lo_bf(xBu); accBhi += ex * hi_bf(xBu); segB += ex;
            iB++;
        }
    }

    uint_t outA = 0u, outB = 0u;
    if (hasA) {
        float inv = 1.0f / segA;
        outA = (uint_t)f2b(accAlo * inv) | ((uint_t)f2b(accAhi * inv) << 16);
    }
    if (hasB) {
        float inv = 1.0f / segB;
        outB = (uint_t)f2b(accBlo * inv) | ((uint_t)f2b(accBhi * inv) << 16);
    }
    AGG64[rA64 + lane] = outA;
    AGG64[rB64 + lane] = outB;
}

// ---------------------------------------------------------------------------
// out[n][i] = relu( sum_r sum_j M[r][i][j] * AGGX[r][n][j] )  — bf16 MFMA,
// fp32 accum. KNOWN GOOD kernel (rounds 5-11); B buffer is now Mb (= U_r
// composed with blockdiag(tovals_r)), consuming x-space aggregates.
// ---------------------------------------------------------------------------
__global__ __launch_bounds__(256) void unify_mfma(
    const ushort_t* __restrict__ AGG,
    const ushort_t* __restrict__ Ub, float* __restrict__ out)
{
    __shared__ ushort_t As[64 * 136];    // A tile: [node][k] bf16
    __shared__ ushort_t Bs[128 * 136];   // B tile: [i][k] bf16

    const int t    = threadIdx.x;
    const int lane = t & 63;
    const int w    = t >> 6;
    const int n0   = blockIdx.x * 64;

    f32x4 acc[8];
    #pragma unroll
    for (int f = 0; f < 8; f++) acc[f] = (f32x4){0.f, 0.f, 0.f, 0.f};

    for (int r = 0; r < N_REL; r++) {
        __syncthreads();

        {   // stage A: AGG[r][n0..n0+63][0..127] plain bf16 copy (16B chunks)
            const uint4* a4 = (const uint4*)(AGG + ((size_t)r * N_NODES + n0) * 128);
            for (int idx = t; idx < 64 * 16; idx += 256) {
                int nn = idx >> 4, c = idx & 15;
                uint4 v = make_uint4(0, 0, 0, 0);
                if (n0 + nn < N_NODES) v = a4[idx];
                *(uint4*)&As[nn * 136 + c * 8] = v;
            }
        }
        {   // stage B: Mb[r] straight copy (L2-hot)
            const uint4* u4 = (const uint4*)(Ub + (size_t)r * 128 * 128);
            for (int idx = t; idx < 128 * 16; idx += 256) {
                int i = idx >> 4, c = idx & 15;
                *(uint4*)&Bs[i * 136 + c * 8] = u4[idx];
            }
        }
        __syncthreads();

        const int row = lane & 15;     // A row / B col
        const int kg  = lane >> 4;     // k-group
        #pragma unroll
        for (int ks = 0; ks < 4; ks++) {
            const int kofs = ks * 32 + kg * 8;
            bf16x8 a = *(const bf16x8*)&As[(w * 16 + row) * 136 + kofs];
            #pragma unroll
            for (int f = 0; f < 8; f++) {
                bf16x8 b = *(const bf16x8*)&Bs[(f * 16 + row) * 136 + kofs];
                acc[f] = __builtin_amdgcn_mfma_f32_16x16x32_bf16(a, b, acc[f], 0, 0, 0);
            }
        }
    }

    const int col  = lane & 15;
    const int rgrp = lane >> 4;
    #pragma unroll
    for (int f = 0; f < 8; f++) {
        #pragma unroll
        for (int reg = 0; reg < 4; reg++) {
            int n = n0 + w * 16 + rgrp * 4 + reg;
            if (n < N_NODES)
                out[(size_t)n * 128 + f * 16 + col] = fmaxf(acc[f][reg], 0.f);
        }
    }
}

extern "C" void kernel_launch(void* const* d_in, const int* in_sizes, int n_in,
                              void* d_out, int out_size, void* d_ws, size_t ws_size,
                              hipStream_t stream)
{
    const float* x  = (const float*)d_in[0];
    const float* tk = (const float*)d_in[1];
    const float* tq = (const float*)d_in[2];
    const float* tv = (const float*)d_in[3];
    const float* un = (const float*)d_in[4];
    const int* esub  = (const int*)d_in[5];
    const int* epred = (const int*)d_in[6];
    const int* eobj  = (const int*)d_in[7];
    float* out = (float*)d_out;

    // Workspace layout (bytes), top = 118,579,840 (< proven 214.66 MB):
    //   KT:   [R][N][128] bf16 (Kt = Ct-projected x)     @ 0            (51,200,000)
    //   XB:   [N][128] bf16 (x cast — the gather target) @ 51,200,000   (12,800,000)
    //   AGG:  [R*N][128] bf16 (x-space aggregates)       @ 64,000,000   (51,200,000)
    //   HIST/CURSOR: [200000] int                        @ 115,200,000  (   800,000)
    //   SUMS: [196] int (pad 4096)                       @ 116,000,000  (     4,096)
    //   SOFF: [196] int (pad 4096)                       @ 116,004,096  (     4,096)
    //   OFFS: [200001] int                               @ 116,008,192  (   800,004 pad->116,816,000)
    //   OBJS: [400000] int                               @ 116,816,000  ( 1,600,000)
    //   Mb:   [R][128][128] bf16 (U·BD(tovals))          @ 118,416,000  (   131,072)
    //   Ct:   [R][H][32][32] bf16 (K^T Q bilinear)       @ 118,547,072  (    32,768)
    char* ws = (char*)d_ws;
    ushort_t* KT  = (ushort_t*)(ws);
    ushort_t* XB  = (ushort_t*)(ws + 51200000);
    ushort_t* AGG = (ushort_t*)(ws + 64000000);
    int*      HIST= (int*)     (ws + 115200000);   // doubles as CURSOR
    int*      SUMS= (int*)     (ws + 116000000);
    int*      SOFF= (int*)     (ws + 116004096);
    int*      OFFS= (int*)     (ws + 116008192);
    int*      OBJS= (int*)     (ws + 116816000);
    ushort_t* Mb  = (ushort_t*)(ws + 118416000);
    ushort_t* Ct  = (ushort_t*)(ws + 118547072);

    // prep: x cast + HIST zero; fused small-matrix products
    prep_kernel<<<(N_NODES * EMBD) / 256, 256, 0, stream>>>(x, XB, HIST);
    fuse_cm<<<320, 256, 0, stream>>>(tk, tq, tv, un, Ct, Mb);

    // CSR build
    hist_kernel<<<(N_EDGE + 255) / 256, 256, 0, stream>>>(esub, epred, HIST);
    scan_p1<<<196, 256, 0, stream>>>(HIST, SUMS);
    scan_p2<<<1, 256, 0, stream>>>(SUMS, SOFF, OFFS);
    scan_p3<<<196, 256, 0, stream>>>(HIST, SOFF, OFFS, HIST);  // OFFS + CURSOR (reuses HIST)
    scatter_kernel<<<(N_EDGE + 255) / 256, 256, 0, stream>>>(esub, epred, eobj, HIST, OBJS);

    // Kt for all relations (single MFMA output — Q and V never materialize)
    proj_mfma<<<(N_NODES + 127) / 128, 512, 0, stream>>>(XB, Ct, KT);

    // fused bilinear-dot + softmax + x-space aggregate (1 gather/edge)
    agg_fused<<<N_ROWS / 8, 256, 0, stream>>>(OFFS, OBJS,
                                              (const uint_t*)KT, (const uint_t*)XB,
                                              (uint_t*)AGG);

    unify_mfma<<<(N_NODES + 63) / 64, 256, 0, stream>>>(AGG, Mb, out);
}

// Round 13
// 174.067 us; speedup vs baseline: 1.1630x; 1.0245x over previous
//
#include <hip/hip_runtime.h>

constexpr int N_NODES = 50000;
constexpr int N_REL   = 4;
constexpr int EMBD    = 128;
constexpr int N_HEAD  = 4;
constexpr int HS      = 32;
constexpr int N_EDGE  = 400000;
constexpr int N_ROWS  = N_REL * N_NODES;        // 200000 segment rows

typedef __attribute__((ext_vector_type(8))) short bf16x8;
typedef __attribute__((ext_vector_type(4))) float f32x4;
typedef unsigned short ushort_t;
typedef unsigned int   uint_t;

__device__ __forceinline__ ushort_t f2b(float f) {
    unsigned int u = __float_as_uint(f);
    u += 0x7FFF + ((u >> 16) & 1);   // round-to-nearest-even
    return (ushort_t)(u >> 16);
}
__device__ __forceinline__ float lo_bf(uint_t u) {   // bf16 pair: low elem
    return __uint_as_float(u << 16);
}
__device__ __forceinline__ float hi_bf(uint_t u) {   // bf16 pair: high elem
    return __uint_as_float(u & 0xFFFF0000u);
}

// ---------------------------------------------------------------------------
// prep (fused): XB = bf16(x) (12.8MB gather target), HIST = 0, and the two
// small fused matrices:
//  Ct[r][h][b][a] = sum_s tokeys[r,h,s,a] * toqueries[r,h,s,b]   (K^T Q form)
//  Mb[r][i][h*32+k] = sum_s unify[r,i,h*32+s] * tovals[r,h,s,k]  (U·BD(tovals))
// One launch replaces prep + fuse_cm.
// ---------------------------------------------------------------------------
__global__ __launch_bounds__(256) void prep_kernel(
    const float* __restrict__ x,
    const float* __restrict__ tk, const float* __restrict__ tq,
    const float* __restrict__ tv, const float* __restrict__ un,
    ushort_t* __restrict__ XB, int* __restrict__ HIST,
    ushort_t* __restrict__ Ct, ushort_t* __restrict__ Mb)
{
    int idx = blockIdx.x * 256 + threadIdx.x;      // grid 25320 = 6481920 threads
    if (idx < N_NODES * EMBD) {
        XB[idx] = f2b(x[idx]);
        if (idx < N_ROWS) HIST[idx] = 0;
    } else {
        int jj = idx - N_NODES * EMBD;             // < 81920
        if (jj < 16384) {
            int a = jj & 31, b = (jj >> 5) & 31, rh = jj >> 10;   // rh = r*4+h
            const float* tks = tk + rh * 1024;     // [s][a]
            const float* tqs = tq + rh * 1024;     // [s][b]
            float acc = 0.f;
            #pragma unroll
            for (int s = 0; s < 32; s++) acc += tks[s * 32 + a] * tqs[s * 32 + b];
            Ct[jj] = f2b(acc);                     // (rh*32 + b)*32 + a
        } else {
            int j  = jj - 16384;                   // Mb flat: [r][i][jc]
            int jc = j & 127, i = (j >> 7) & 127, r = j >> 14;
            int h = jc >> 5, k = jc & 31;
            const float* us  = un + ((size_t)(r * 128 + i)) * 128 + h * 32;
            const float* tvs = tv + (r * 4 + h) * 1024 + k;
            float acc = 0.f;
            #pragma unroll
            for (int s = 0; s < 32; s++) acc += us[s] * tvs[s * 32];
            Mb[j] = f2b(acc);
        }
    }
}

// ---------------------------------------------------------------------------
// MFMA projection: Kt[r][n][h*32+b] = sum_a Ct[r,h,b,a]*x[n,h*32+a].
// KNOWN GOOD (r12; fragment maps proven r5-12).
// ---------------------------------------------------------------------------
__global__ __launch_bounds__(512) void proj_mfma(
    const ushort_t* __restrict__ XB, const ushort_t* __restrict__ Ct,
    ushort_t* __restrict__ KT)
{
    __shared__ ushort_t xs[128 * 136];   // [node][k] bf16, stride 272B

    const int t    = threadIdx.x;        // 0..511
    const int lane = t & 63;
    const int w    = t >> 6;             // wave 0..7
    const int n0   = blockIdx.x * 128;

    {   // stage XB tile (bf16, 16B chunks)
        const uint4* x4 = (const uint4*)(XB + (size_t)n0 * 128);
        for (int idx = t; idx < 128 * 16; idx += 512) {
            int nn = idx >> 4, c = idx & 15;
            uint4 v = make_uint4(0, 0, 0, 0);
            if (n0 + nn < N_NODES) v = x4[idx];
            *(uint4*)&xs[nn * 136 + c * 8] = v;
        }
    }
    __syncthreads();

    const int row  = lane & 15;     // A node-row / B col / D col
    const int kg   = lane >> 4;     // k-group (8 elems each)
    const int rgrp = lane >> 4;     // D row-group

    #pragma unroll 1
    for (int r = 0; r < N_REL; r++) {
        f32x4 acc[8];
        #pragma unroll
        for (int f = 0; f < 8; f++) {
            const int h = f >> 1;
            bf16x8 a = *(const bf16x8*)&xs[(w * 16 + row) * 136 + h * 32 + kg * 8];
            const ushort_t* bp = Ct + (((r * 4 + h) * 32 + (f & 1) * 16 + row) * 32) + kg * 8;
            bf16x8 b = *(const bf16x8*)bp;
            acc[f] = __builtin_amdgcn_mfma_f32_16x16x32_bf16(
                         a, b, (f32x4){0.f, 0.f, 0.f, 0.f}, 0, 0, 0);
        }
        #pragma unroll
        for (int f = 0; f < 8; f++) {
            #pragma unroll
            for (int reg = 0; reg < 4; reg++) {
                int n = n0 + w * 16 + rgrp * 4 + reg;
                if (n < N_NODES)
                    KT[((size_t)r * N_NODES + n) * 128 + f * 16 + row] = f2b(acc[f][reg]);
            }
        }
    }
}

// ---------------------------------------------------------------------------
// CSR build: histogram -> 3-phase deterministic scan -> scatter. KNOWN GOOD.
// ---------------------------------------------------------------------------
__global__ __launch_bounds__(256) void hist_kernel(
    const int* __restrict__ esub, const int* __restrict__ epred, int* __restrict__ HIST)
{
    int e = blockIdx.x * 256 + threadIdx.x;
    if (e < N_EDGE) atomicAdd(&HIST[epred[e] * N_NODES + esub[e]], 1);
}

__global__ __launch_bounds__(256) void scan_p1(      // per-block totals
    const int* __restrict__ HIST, int* __restrict__ SUMS)
{
    int b = blockIdx.x, t = threadIdx.x;
    int base = b * 1024 + t * 4;
    int s = 0;
    #pragma unroll
    for (int k = 0; k < 4; k++) if (base + k < N_ROWS) s += HIST[base + k];
    __shared__ int red[256];
    red[t] = s; __syncthreads();
    for (int st = 128; st > 0; st >>= 1) {
        if (t < st) red[t] += red[t + st];
        __syncthreads();
    }
    if (t == 0) SUMS[b] = red[0];
}

__global__ __launch_bounds__(256) void scan_p2(      // scan the 196 totals
    const int* __restrict__ SUMS, int* __restrict__ SOFF, int* __restrict__ OFFS)
{
    int t = threadIdx.x;
    __shared__ int sh[256];
    int o = (t < 196) ? SUMS[t] : 0;
    sh[t] = o; __syncthreads();
    for (int st = 1; st < 256; st <<= 1) {
        int v = (t >= st) ? sh[t - st] : 0;
        __syncthreads();
        sh[t] += v;
        __syncthreads();
    }
    if (t < 196) SOFF[t] = sh[t] - o;                // exclusive
    if (t == 0)  OFFS[N_ROWS] = sh[255];             // total == N_EDGE
}

__global__ __launch_bounds__(256) void scan_p3(      // full exclusive scan (+CURSOR)
    const int* __restrict__ HIST, const int* __restrict__ SOFF,
    int* __restrict__ OFFS, int* __restrict__ CURSOR)
{
    int b = blockIdx.x, t = threadIdx.x;
    int base = b * 1024 + t * 4;
    int v[4], tot = 0;
    #pragma unroll
    for (int k = 0; k < 4; k++) {
        v[k] = (base + k < N_ROWS) ? HIST[base + k] : 0;
        tot += v[k];
    }
    __shared__ int sh[256];
    sh[t] = tot; __syncthreads();
    for (int st = 1; st < 256; st <<= 1) {
        int q = (t >= st) ? sh[t - st] : 0;
        __syncthreads();
        sh[t] += q;
        __syncthreads();
    }
    int run = SOFF[b] + (sh[t] - tot);
    #pragma unroll
    for (int k = 0; k < 4; k++) {
        if (base + k < N_ROWS) { OFFS[base + k] = run; CURSOR[base + k] = run; run += v[k]; }
    }
}

__global__ __launch_bounds__(256) void scatter_kernel(
    const int* __restrict__ esub, const int* __restrict__ epred, const int* __restrict__ eobj,
    int* __restrict__ CURSOR, int* __restrict__ OBJS)
{
    int e = blockIdx.x * 256 + threadIdx.x;
    if (e < N_EDGE) {
        int row = epred[e] * N_NODES + esub[e];
        int pos = atomicAdd(&CURSOR[row], 1);
        OBJS[pos] = eobj[e];                       // store obj, not edge id
    }
}

// ---------------------------------------------------------------------------
// FUSED dot+softmax+aggregate in X-SPACE, FOUR rows per wave (rows 4b..4b+3,
// 5 shared OFFS loads). 4 independent gather chains in flight (2x the MLP of
// r11/12's 2-row version; per-EDGE issue cost unchanged). Per edge: ONE 256B
// gather of x_obj from the L2/L3-resident 12.8MB XB buffer feeds BOTH the
// bilinear dot (vs row-local Kt) and the aggregation.
// All per-row state in fully-unrolled constant-indexed arrays (no scratch).
// ---------------------------------------------------------------------------
__global__ __launch_bounds__(256) void agg_fused(
    const int* __restrict__ OFFS, const int* __restrict__ OBJS,
    const uint_t* __restrict__ KT64, const uint_t* __restrict__ XB64,
    uint_t* __restrict__ AGG64)
{
    const int t    = threadIdx.x;
    const int lane = t & 63;
    const int row0 = (blockIdx.x * 4 + (t >> 6)) * 4;   // grid 12500: 200000 rows

    int off[5];
    #pragma unroll
    for (int q = 0; q < 5; q++) off[q] = OFFS[row0 + q];

    float klo[4], khi[4], aclo[4], achi[4], seg[4];
    int   it[4];
    #pragma unroll
    for (int q = 0; q < 4; q++) {
        it[q] = off[q];
        aclo[q] = 0.f; achi[q] = 0.f; seg[q] = 0.f;
        klo[q] = 0.f;  khi[q] = 0.f;
        if (off[q] < off[q + 1]) {
            uint_t ku = KT64[(unsigned)(row0 + q) * 64u + lane];
            klo[q] = lo_bf(ku); khi[q] = hi_bf(ku);
        }
    }

    while (it[0] < off[1] || it[1] < off[2] || it[2] < off[3] || it[3] < off[4]) {
        uint_t xu[4];
        bool   d[4];
        #pragma unroll
        for (int q = 0; q < 4; q++) {               // issue all 4 gathers first
            d[q]  = it[q] < off[q + 1];
            xu[q] = 0;
            if (d[q]) xu[q] = XB64[(unsigned)OBJS[it[q]] * 64u + lane];
        }
        float p[4];
        #pragma unroll
        for (int q = 0; q < 4; q++)
            p[q] = klo[q] * lo_bf(xu[q]) + khi[q] * hi_bf(xu[q]);
        #pragma unroll
        for (int m = 1; m < 16; m <<= 1) {          // 16-lane (one head) butterfly
            #pragma unroll
            for (int q = 0; q < 4; q++) p[q] += __shfl_xor(p[q], m, 64);
        }
        #pragma unroll
        for (int q = 0; q < 4; q++) {
            if (d[q]) {
                float ex = __expf(p[q]);
                aclo[q] += ex * lo_bf(xu[q]);
                achi[q] += ex * hi_bf(xu[q]);
                seg[q]  += ex;
                it[q]++;
            }
        }
    }

    #pragma unroll
    for (int q = 0; q < 4; q++) {
        uint_t o = 0u;
        if (off[q] < off[q + 1]) {
            float inv = 1.0f / seg[q];
            o = (uint_t)f2b(aclo[q] * inv) | ((uint_t)f2b(achi[q] * inv) << 16);
        }
        AGG64[(unsigned)(row0 + q) * 64u + lane] = o;
    }
}

// ---------------------------------------------------------------------------
// out[n][i] = relu( sum_r sum_j M[r][i][j] * AGGX[r][n][j] )  — bf16 MFMA,
// fp32 accum. KNOWN GOOD (rounds 5-12); B = Mb (U·BD(tovals)).
// ---------------------------------------------------------------------------
__global__ __launch_bounds__(256) void unify_mfma(
    const ushort_t* __restrict__ AGG,
    const ushort_t* __restrict__ Ub, float* __restrict__ out)
{
    __shared__ ushort_t As[64 * 136];    // A tile: [node][k] bf16
    __shared__ ushort_t Bs[128 * 136];   // B tile: [i][k] bf16

    const int t    = threadIdx.x;
    const int lane = t & 63;
    const int w    = t >> 6;
    const int n0   = blockIdx.x * 64;

    f32x4 acc[8];
    #pragma unroll
    for (int f = 0; f < 8; f++) acc[f] = (f32x4){0.f, 0.f, 0.f, 0.f};

    for (int r = 0; r < N_REL; r++) {
        __syncthreads();

        {   // stage A: AGG[r][n0..n0+63][0..127] plain bf16 copy (16B chunks)
            const uint4* a4 = (const uint4*)(AGG + ((size_t)r * N_NODES + n0) * 128);
            for (int idx = t; idx < 64 * 16; idx += 256) {
                int nn = idx >> 4, c = idx & 15;
                uint4 v = make_uint4(0, 0, 0, 0);
                if (n0 + nn < N_NODES) v = a4[idx];
                *(uint4*)&As[nn * 136 + c * 8] = v;
            }
        }
        {   // stage B: Mb[r] straight copy (L2-hot)
            const uint4* u4 = (const uint4*)(Ub + (size_t)r * 128 * 128);
            for (int idx = t; idx < 128 * 16; idx += 256) {
                int i = idx >> 4, c = idx & 15;
                *(uint4*)&Bs[i * 136 + c * 8] = u4[idx];
            }
        }
        __syncthreads();

        const int row = lane & 15;     // A row / B col
        const int kg  = lane >> 4;     // k-group
        #pragma unroll
        for (int ks = 0; ks < 4; ks++) {
            const int kofs = ks * 32 + kg * 8;
            bf16x8 a = *(const bf16x8*)&As[(w * 16 + row) * 136 + kofs];
            #pragma unroll
            for (int f = 0; f < 8; f++) {
                bf16x8 b = *(const bf16x8*)&Bs[(f * 16 + row) * 136 + kofs];
                acc[f] = __builtin_amdgcn_mfma_f32_16x16x32_bf16(a, b, acc[f], 0, 0, 0);
            }
        }
    }

    const int col  = lane & 15;
    const int rgrp = lane >> 4;
    #pragma unroll
    for (int f = 0; f < 8; f++) {
        #pragma unroll
        for (int reg = 0; reg < 4; reg++) {
            int n = n0 + w * 16 + rgrp * 4 + reg;
            if (n < N_NODES)
                out[(size_t)n * 128 + f * 16 + col] = fmaxf(acc[f][reg], 0.f);
        }
    }
}

extern "C" void kernel_launch(void* const* d_in, const int* in_sizes, int n_in,
                              void* d_out, int out_size, void* d_ws, size_t ws_size,
                              hipStream_t stream)
{
    const float* x  = (const float*)d_in[0];
    const float* tk = (const float*)d_in[1];
    const float* tq = (const float*)d_in[2];
    const float* tv = (const float*)d_in[3];
    const float* un = (const float*)d_in[4];
    const int* esub  = (const int*)d_in[5];
    const int* epred = (const int*)d_in[6];
    const int* eobj  = (const int*)d_in[7];
    float* out = (float*)d_out;

    // Workspace layout (bytes), identical to round 12 (proven):
    //   KT:   [R][N][128] bf16 (Kt = Ct-projected x)     @ 0            (51,200,000)
    //   XB:   [N][128] bf16 (x cast — the gather target) @ 51,200,000   (12,800,000)
    //   AGG:  [R*N][128] bf16 (x-space aggregates)       @ 64,000,000   (51,200,000)
    //   HIST/CURSOR: [200000] int                        @ 115,200,000  (   800,000)
    //   SUMS: [196] int (pad 4096)                       @ 116,000,000  (     4,096)
    //   SOFF: [196] int (pad 4096)                       @ 116,004,096  (     4,096)
    //   OFFS: [200001] int                               @ 116,008,192  (   800,004 pad->116,816,000)
    //   OBJS: [400000] int                               @ 116,816,000  ( 1,600,000)
    //   Mb:   [R][128][128] bf16 (U·BD(tovals))          @ 118,416,000  (   131,072)
    //   Ct:   [R][H][32][32] bf16 (K^T Q bilinear)       @ 118,547,072  (    32,768)
    char* ws = (char*)d_ws;
    ushort_t* KT  = (ushort_t*)(ws);
    ushort_t* XB  = (ushort_t*)(ws + 51200000);
    ushort_t* AGG = (ushort_t*)(ws + 64000000);
    int*      HIST= (int*)     (ws + 115200000);   // doubles as CURSOR
    int*      SUMS= (int*)     (ws + 116000000);
    int*      SOFF= (int*)     (ws + 116004096);
    int*      OFFS= (int*)     (ws + 116008192);
    int*      OBJS= (int*)     (ws + 116816000);
    ushort_t* Mb  = (ushort_t*)(ws + 118416000);
    ushort_t* Ct  = (ushort_t*)(ws + 118547072);

    // prep (fused): x cast + HIST zero + Ct/Mb small-matrix products
    prep_kernel<<<(N_NODES * EMBD + 81920) / 256, 256, 0, stream>>>(
        x, tk, tq, tv, un, XB, HIST, Ct, Mb);

    // CSR build
    hist_kernel<<<(N_EDGE + 255) / 256, 256, 0, stream>>>(esub, epred, HIST);
    scan_p1<<<196, 256, 0, stream>>>(HIST, SUMS);
    scan_p2<<<1, 256, 0, stream>>>(SUMS, SOFF, OFFS);
    scan_p3<<<196, 256, 0, stream>>>(HIST, SOFF, OFFS, HIST);  // OFFS + CURSOR (reuses HIST)
    scatter_kernel<<<(N_EDGE + 255) / 256, 256, 0, stream>>>(esub, epred, eobj, HIST, OBJS);

    // Kt for all relations (single MFMA output — Q and V never materialize)
    proj_mfma<<<(N_NODES + 127) / 128, 512, 0, stream>>>(XB, Ct, KT);

    // fused bilinear-dot + softmax + x-space aggregate (4 rows/wave, 1 gather/edge)
    agg_fused<<<N_ROWS / 16, 256, 0, stream>>>(OFFS, OBJS,
                                               (const uint_t*)KT, (const uint_t*)XB,
                                               (uint_t*)AGG);

    unify_mfma<<<(N_NODES + 63) / 64, 256, 0, stream>>>(AGG, Mb, out);
}